// Round 9
// baseline (1068.887 us; speedup 1.0000x reference)
//
#include <hip/hip_runtime.h>

#define B_    128
#define N_    64
#define D_    64
#define A_    12
#define H_    128
#define E_    4032   // N*(N-1)
#define AA_   144    // A*A
#define ITERS_ 8
#define ET    128    // edge tile (edge-vals kernel)
#define EB    32     // edges per block (msg kernel)
#define KC    32     // K-chunk in k_edge. PINNED: KC=32 measured 140us;
                     // KC=16 -> 147us (R7), reg-prefetch -> 158us (R6). Do not "optimize".
#define SC    32     // sub-chunk for the msg loop: ev half (74MB) stays LLC-resident

typedef float f4_t __attribute__((ext_vector_type(4)));

// e -> (from,to): pairs are i-major, j skipping i
__device__ __forceinline__ void edge_nodes(int e, int& fr, int& to) {
    fr = e / 63;
    int rr = e - fr * 63;
    to = rr + (rr >= fr ? 1 : 0);
}

// ---------------------------------------------------------------------------
// Kernel 1: per-(b,n) node MLP + edge-GEMM1 decomposition. Writes a_hist[0].
// ---------------------------------------------------------------------------
__global__ __launch_bounds__(128) void k_node(
    const float* __restrict__ obs,
    const float* __restrict__ W1n, const float* __restrict__ b1n,
    const float* __restrict__ W2n, const float* __restrict__ b2n,
    const float* __restrict__ W1e, const float* __restrict__ b1e,
    float* __restrict__ Hf, float* __restrict__ Ht,
    float* __restrict__ nv, float* __restrict__ q, int* __restrict__ a0,
    int b0)
{
    int bn = blockIdx.x;      // local (b*64+n)
    int t  = threadIdx.x;     // 0..127
    __shared__ float s_obs[D_];
    __shared__ float s_hid[H_];
    __shared__ float s_nv[A_];
    if (t < D_) s_obs[t] = obs[(size_t)(b0 * N_ + bn) * D_ + t];
    __syncthreads();
    float an  = b1n[t];
    float af  = b1e[t];
    float at_ = 0.f;
    for (int k = 0; k < D_; ++k) {
        float o = s_obs[k];
        an  = fmaf(o, W1n[k * H_ + t], an);
        af  = fmaf(o, W1e[k * H_ + t], af);
        at_ = fmaf(o, W1e[(D_ + k) * H_ + t], at_);
    }
    s_hid[t] = fmaxf(an, 0.f);
    Hf[bn * H_ + t] = af;
    Ht[bn * H_ + t] = at_;
    __syncthreads();
    if (t < A_) {
        float acc = b2n[t];
        for (int k = 0; k < H_; ++k) acc = fmaf(s_hid[k], W2n[k * A_ + t], acc);
        s_nv[t] = acc;
        nv[bn * A_ + t] = acc;
        q[bn * A_ + t]  = acc * (1.0f / N_);
    }
    __syncthreads();
    if (t == 0) {
        float best = s_nv[0]; int bi = 0;
        for (int a = 1; a < A_; ++a) if (s_nv[a] > best) { best = s_nv[a]; bi = a; }
        a0[bn] = bi;
    }
}

// ---------------------------------------------------------------------------
// Kernel 2: edge_vals = relu(Hf[from]+Ht[to]) @ W2e + b2e.
// EXACT round-5 structure (KC=32, plain staged loop): measured 140us. PINNED.
// ---------------------------------------------------------------------------
__global__ __launch_bounds__(192) void k_edge(
    const float* __restrict__ Hf, const float* __restrict__ Ht,
    const float* __restrict__ W2e, const float* __restrict__ b2e,
    float* __restrict__ ev)
{
    __shared__ float s_w[KC * AA_];
    __shared__ float s_hT[KC * ET];
    __shared__ float s_b2[AA_];
    int t  = threadIdx.x;
    int b  = blockIdx.y;              // local batch
    int e0 = blockIdx.x * ET;
    int nE = min(ET, E_ - e0);

    if (t < AA_) s_b2[t] = b2e[t];

    int e_a = t & 127, kq_a = t >> 7;
    int fr_a = 0, to_a = 0;
    bool va = (e_a < nE);
    if (va) edge_nodes(e0 + e_a, fr_a, to_a);
    bool hb = (t < 64);
    int e_b = t + 64;
    int fr_b = 0, to_b = 0;
    bool vb = hb && (e_b < nE);
    if (vb) edge_nodes(e0 + e_b, fr_b, to_b);

    const float* HfB = Hf + (size_t)b * N_ * H_;
    const float* HtB = Ht + (size_t)b * N_ * H_;

    int cg = t % 12, rg = t / 12, rbase = rg * 8;
    float acc[8][12];
#pragma unroll
    for (int i = 0; i < 8; ++i)
#pragma unroll
        for (int j = 0; j < 12; ++j) acc[i][j] = 0.f;

    for (int kc = 0; kc < H_ / KC; ++kc) {
        __syncthreads();   // protect previous chunk's reads before overwrite
        const f4_t* wsrc = (const f4_t*)(W2e + kc * KC * AA_);
#pragma unroll
        for (int i = 0; i < 6; ++i)
            *(f4_t*)&s_w[(t + i * 192) * 4] = wsrc[t + i * 192];
        {
            int kk = kc * KC + kq_a * 16;
            if (va) {
                const f4_t* pf = (const f4_t*)(HfB + fr_a * H_ + kk);
                const f4_t* pt = (const f4_t*)(HtB + to_a * H_ + kk);
#pragma unroll
                for (int m = 0; m < 4; ++m) {
                    f4_t x = pf[m], y = pt[m];
                    s_hT[(kq_a * 16 + 4 * m + 0) * ET + e_a] = fmaxf(x.x + y.x, 0.f);
                    s_hT[(kq_a * 16 + 4 * m + 1) * ET + e_a] = fmaxf(x.y + y.y, 0.f);
                    s_hT[(kq_a * 16 + 4 * m + 2) * ET + e_a] = fmaxf(x.z + y.z, 0.f);
                    s_hT[(kq_a * 16 + 4 * m + 3) * ET + e_a] = fmaxf(x.w + y.w, 0.f);
                }
            } else {
#pragma unroll
                for (int m = 0; m < 16; ++m) s_hT[(kq_a * 16 + m) * ET + e_a] = 0.f;
            }
            if (hb) {
                int kk2 = kc * KC + 16;
                if (vb) {
                    const f4_t* pf = (const f4_t*)(HfB + fr_b * H_ + kk2);
                    const f4_t* pt = (const f4_t*)(HtB + to_b * H_ + kk2);
#pragma unroll
                    for (int m = 0; m < 4; ++m) {
                        f4_t x = pf[m], y = pt[m];
                        s_hT[(16 + 4 * m + 0) * ET + e_b] = fmaxf(x.x + y.x, 0.f);
                        s_hT[(16 + 4 * m + 1) * ET + e_b] = fmaxf(x.y + y.y, 0.f);
                        s_hT[(16 + 4 * m + 2) * ET + e_b] = fmaxf(x.z + y.z, 0.f);
                        s_hT[(16 + 4 * m + 3) * ET + e_b] = fmaxf(x.w + y.w, 0.f);
                    }
                } else {
#pragma unroll
                    for (int m = 0; m < 16; ++m) s_hT[(16 + m) * ET + e_b] = 0.f;
                }
            }
        }
        __syncthreads();

#pragma unroll 2
        for (int k = 0; k < KC; ++k) {
            const float* hp = &s_hT[k * ET + rbase];
            f4_t h0 = *(const f4_t*)hp;
            f4_t h1 = *(const f4_t*)(hp + 4);
            const float* wp = &s_w[k * AA_ + cg * 12];
            f4_t w0 = *(const f4_t*)wp;
            f4_t w1 = *(const f4_t*)(wp + 4);
            f4_t w2 = *(const f4_t*)(wp + 8);
            float hv[8]  = {h0.x,h0.y,h0.z,h0.w,h1.x,h1.y,h1.z,h1.w};
            float wv[12] = {w0.x,w0.y,w0.z,w0.w,w1.x,w1.y,w1.z,w1.w,w2.x,w2.y,w2.z,w2.w};
#pragma unroll
            for (int i = 0; i < 8; ++i)
#pragma unroll
                for (int j = 0; j < 12; ++j)
                    acc[i][j] = fmaf(hv[i], wv[j], acc[i][j]);
        }
    }

    size_t obase = (size_t)(b * E_ + e0) * AA_;
#pragma unroll
    for (int i = 0; i < 8; ++i) {
        int e = rbase + i;
        if (e < nE) {
            float* op = &ev[obase + (size_t)e * AA_ + cg * 12];
#pragma unroll
            for (int j = 0; j < 12; j += 4) {
                f4_t o;
                o.x = acc[i][j + 0] + s_b2[cg * 12 + j + 0];
                o.y = acc[i][j + 1] + s_b2[cg * 12 + j + 1];
                o.z = acc[i][j + 2] + s_b2[cg * 12 + j + 2];
                o.w = acc[i][j + 3] + s_b2[cg * 12 + j + 3];
                *(f4_t*)(op + j) = o;
            }
        }
    }
}

// ---------------------------------------------------------------------------
// Kernel 3: fused fwd+bwd message update (R7 dual-write form — PINNED:
// mfT-gather variant was 27us slower, R8). ev rows in registers; f4 staging.
// ---------------------------------------------------------------------------
__global__ __launch_bounds__(128) void k_msg(
    const float* __restrict__ ev, const float* __restrict__ q,
    float* __restrict__ mf, float* __restrict__ mfT,
    float* __restrict__ mb, int first)
{
    __shared__ float s_c1[EB * A_], s_c2[EB * A_];
    __shared__ float s_mf[EB * A_], s_mb[EB * A_];
    int t  = threadIdx.x;
    int b  = blockIdx.y;
    int e0 = blockIdx.x * EB;

    // staging: 96 f4 per array (32 edges x 12 floats)
    if (t < 96) {
        int e = t / 3, m = t - (t / 3) * 3;
        int eg = e0 + e, fr, to; edge_nodes(eg, fr, to);
        f4_t qf = ((const f4_t*)(q + ((size_t)b * N_ + fr) * A_))[m];
        f4_t qt = ((const f4_t*)(q + ((size_t)b * N_ + to) * A_))[m];
        if (!first) {
            f4_t mbo = ((const f4_t*)(mb + ((size_t)b * E_ + e0) * A_))[t];
            f4_t mfo = ((const f4_t*)(mf + ((size_t)b * E_ + e0) * A_))[t];
            qf.x -= mbo.x; qf.y -= mbo.y; qf.z -= mbo.z; qf.w -= mbo.w;
            qt.x -= mfo.x; qt.y -= mfo.y; qt.z -= mfo.z; qt.w -= mfo.w;
        }
        ((f4_t*)s_c1)[t] = qf;
        ((f4_t*)s_c2)[t] = qt;
    }

    int e = t >> 2, s = t & 3;
    int eg = e0 + e, fr_o, to_o; edge_nodes(eg, fr_o, to_o);
    const float* wp = ev + ((size_t)(b * E_ + eg)) * AA_ + s * 36;
    f4_t wv[9];
#pragma unroll
    for (int i = 0; i < 9; ++i) wv[i] = ((const f4_t*)wp)[i];
    __syncthreads();

    const float invE = 1.0f / (float)E_;
    float fo[12];
#pragma unroll
    for (int j = 0; j < 12; ++j) fo[j] = -1e30f;
#pragma unroll
    for (int r = 0; r < 3; ++r) {
        float c1v = s_c1[e * A_ + s * 3 + r];
#pragma unroll
        for (int j = 0; j < 12; ++j) {
            int li = r * 12 + j;
            float w = wv[li >> 2][li & 3];
            fo[j] = fmaxf(fo[j], c1v + w * invE);
        }
    }
#pragma unroll
    for (int j = 0; j < 12; ++j) {
        float v = fo[j];
        v = fmaxf(v, __shfl_xor(v, 1));
        v = fmaxf(v, __shfl_xor(v, 2));
        fo[j] = v;
    }
    float fsum = 0.f;
#pragma unroll
    for (int i = 0; i < 3; ++i) fsum += fo[s * 3 + i];
    fsum += __shfl_xor(fsum, 1); fsum += __shfl_xor(fsum, 2);
    float fmean = fsum / 12.0f;

    float c2r[12];
#pragma unroll
    for (int j = 0; j < 12; ++j) c2r[j] = s_c2[e * A_ + j];
    float ba[3];
    float bsum = 0.f;
#pragma unroll
    for (int r = 0; r < 3; ++r) {
        float m = -1e30f;
#pragma unroll
        for (int j = 0; j < 12; ++j) {
            int li = r * 12 + j;
            float w = wv[li >> 2][li & 3];
            m = fmaxf(m, c2r[j] + w * invE);
        }
        ba[r] = m; bsum += m;
    }
    bsum += __shfl_xor(bsum, 1); bsum += __shfl_xor(bsum, 2);
    float bmean = bsum / 12.0f;

#pragma unroll
    for (int i = 0; i < 3; ++i) {
        s_mf[e * A_ + s * 3 + i] = fo[s * 3 + i] - fmean;
        s_mb[e * A_ + s * 3 + i] = ba[i] - bmean;
    }
    // mfT: to-major layout, rank = fr - (fr>to); 4 threads write 48B/edge
    {
        int rr2 = fr_o - (fr_o > to_o ? 1 : 0);
        float* mtp = mfT + (((size_t)b * N_ + to_o) * 63 + rr2) * A_ + s * 3;
        mtp[0] = fo[s * 3 + 0] - fmean;
        mtp[1] = fo[s * 3 + 1] - fmean;
        mtp[2] = fo[s * 3 + 2] - fmean;
    }
    __syncthreads();
    if (t < 96) {
        size_t gbase = (size_t)(b * E_ + e0) * A_;
        ((f4_t*)(mf + gbase))[t] = ((f4_t*)s_mf)[t];
        ((f4_t*)(mb + gbase))[t] = ((f4_t*)s_mb)[t];
    }
}

// ---------------------------------------------------------------------------
// Kernel 4: q = nv/N + seq-sum(mfT row) + seq-sum(mb row); argmax -> a_out.
// ---------------------------------------------------------------------------
__global__ __launch_bounds__(256) void k_qupd(
    const float* __restrict__ nv, const float* __restrict__ mfT,
    const float* __restrict__ mb,
    float* __restrict__ q, int* __restrict__ a_out)
{
    __shared__ float s_f[8 * 756];
    __shared__ float s_b[8 * 756];
    __shared__ float s_q[8][A_];
    int t  = threadIdx.x;
    int b  = blockIdx.y;
    int n0 = blockIdx.x * 8;
    const f4_t* src_f = (const f4_t*)(mfT + ((size_t)b * N_ + n0) * 63 * A_);
    const f4_t* src_b = (const f4_t*)(mb + ((size_t)b * E_ + n0 * 63) * A_);
#pragma unroll
    for (int i = 0; i < 6; ++i) {
        int gi = t + i * 256;                  // 1512 f4 total
        if (gi < 1512) {
            ((f4_t*)s_f)[gi] = src_f[gi];
            ((f4_t*)s_b)[gi] = src_b[gi];
        }
    }
    __syncthreads();
    int nl = t / 12, a = t - nl * 12;
    if (t < 96) {
        int n = n0 + nl;
        float acc = nv[(b * N_ + n) * A_ + a] * (1.0f / N_);
        const float* pf = s_f + nl * 756 + a;
        for (int i = 0; i < 63; ++i) acc += pf[i * 12];
        const float* pb = s_b + nl * 756 + a;
        for (int i = 0; i < 63; ++i) acc += pb[i * 12];
        q[(b * N_ + n) * A_ + a] = acc;
        s_q[nl][a] = acc;
    }
    __syncthreads();
    if (t < 8) {
        float best = s_q[t][0]; int bi = 0;
        for (int aa = 1; aa < A_; ++aa) if (s_q[t][aa] > best) { best = s_q[t][aa]; bi = aa; }
        a_out[b * N_ + n0 + t] = bi;
    }
}

// ---------------------------------------------------------------------------
// Kernel 5: stream ev rows once; 9 waves = 9 candidates; fp64 tile partials.
// ---------------------------------------------------------------------------
__global__ __launch_bounds__(576) void k_evalx(
    const float* __restrict__ ev, const int* __restrict__ a_hist,
    double* __restrict__ qpart, int Cb)
{
    __shared__ float s_ev[64 * 148];
    __shared__ int   s_aa[9][N_];
    int t = threadIdx.x, tile = blockIdx.x, b = blockIdx.y;
    const f4_t* src = (const f4_t*)(ev + ((size_t)b * E_ + tile * 64) * AA_);
#pragma unroll
    for (int i = 0; i < 4; ++i) {
        int gi = t + i * 576;                  // 2304 f4 exactly
        int e = gi / 36, k = gi - e * 36;
        *(f4_t*)&s_ev[e * 148 + k * 4] = src[gi];
    }
    s_aa[t / 64][t % 64] = a_hist[((size_t)(t / 64) * Cb + b) * N_ + (t % 64)];
    __syncthreads();
    int c = t / 64, el = t % 64;
    int eg = tile * 64 + el;
    int fr, to; edge_nodes(eg, fr, to);
    double v = (double)s_ev[el * 148 + s_aa[c][fr] * A_ + s_aa[c][to]];
#pragma unroll
    for (int off = 1; off < 64; off <<= 1) v += __shfl_xor(v, off);
    if (el == 0) qpart[((size_t)b * 63 + tile) * 9 + c] = v;
}

// ---------------------------------------------------------------------------
// Kernel 6: per-b: fp64 candidate totals (tiles asc + nv part), strict-> scan.
// ---------------------------------------------------------------------------
__global__ __launch_bounds__(64) void k_select(
    const double* __restrict__ qpart, const float* __restrict__ nv,
    const int* __restrict__ a_hist, float* __restrict__ out, int b0, int Cb)
{
    int b = blockIdx.x, t = threadIdx.x;
    __shared__ double s_qv[9];
    __shared__ int s_best;
    if (t < 9) {
        double s = 0.0;
        const double* qp = qpart + (size_t)b * 63 * 9 + t;
        for (int i = 0; i < 63; ++i) s += qp[i * 9];
        const int* ah = a_hist + ((size_t)t * Cb + b) * N_;
        const float* nb = nv + (size_t)b * N_ * A_;
        double ns = 0.0;
        for (int n = 0; n < N_; ++n) ns += (double)nb[n * A_ + ah[n]];
        s_qv[t] = ns / 64.0 + s / 4032.0;
    }
    __syncthreads();
    if (t == 0) {
        double best = s_qv[0]; int bi = 0;
        for (int c = 1; c <= ITERS_; ++c) if (s_qv[c] > best) { best = s_qv[c]; bi = c; }
        out[b0 + b] = (float)best;
        s_best = bi;
    }
    __syncthreads();
    out[B_ + (size_t)(b0 + b) * N_ + t] = (float)a_hist[((size_t)s_best * Cb + b) * N_ + t];
}

// Diagnostic: encode ws_size (MB) into out[0] so a failed absmax reveals it.
__global__ void k_diag(float* out, float v, int n) {
    int i = blockIdx.x * 256 + threadIdx.x;
    if (i < n) out[i] = (i == 0) ? v : -10000.0f;
}

extern "C" void kernel_launch(void* const* d_in, const int* in_sizes, int n_in,
                              void* d_out, int out_size, void* d_ws, size_t ws_size,
                              hipStream_t stream) {
    const float* obs = (const float*)d_in[0];
    const float* W1n = (const float*)d_in[1];
    const float* b1n = (const float*)d_in[2];
    const float* W2n = (const float*)d_in[3];
    const float* b2n = (const float*)d_in[4];
    const float* W1e = (const float*)d_in[5];
    const float* b1e = (const float*)d_in[6];
    const float* W2e = (const float*)d_in[7];
    const float* b2e = (const float*)d_in[8];
    float* out = (float*)d_out;
    (void)in_sizes; (void)n_in; (void)out_size;

    // per-batch bytes: Hf+Ht 65536, nv+q 6144, mf+mfT+mb 580608, a_hist 2304,
    // qpart 4536, ev 2322432 => 2981560; plus per-buffer align slack
    auto need = [](int Cb) -> size_t { return (size_t)Cb * 2981560u + 16384u; };

    int Cb = 0;
    for (int c = B_; c >= 8; c >>= 1) {
        if (ws_size >= need(c)) { Cb = c; break; }
    }
    if (Cb == 0) {
        k_diag<<<(B_ + B_ * N_ + 255) / 256, 256, 0, stream>>>(
            out, (float)(ws_size >> 20), B_ + B_ * N_);
        return;
    }

    char* ws = (char*)d_ws;
    size_t off = 0;
    auto alloc = [&](size_t bytes) { void* p = ws + off; off += (bytes + 255) & ~(size_t)255; return p; };
    float*  Hf     = (float*) alloc((size_t)Cb * N_ * H_ * 4);
    float*  Ht     = (float*) alloc((size_t)Cb * N_ * H_ * 4);
    float*  nv     = (float*) alloc((size_t)Cb * N_ * A_ * 4);
    float*  q      = (float*) alloc((size_t)Cb * N_ * A_ * 4);
    float*  mf     = (float*) alloc((size_t)Cb * E_ * A_ * 4);
    float*  mfT    = (float*) alloc((size_t)Cb * N_ * 63 * A_ * 4);
    float*  mb     = (float*) alloc((size_t)Cb * E_ * A_ * 4);
    int*    a_hist = (int*)   alloc((size_t)(1 + ITERS_) * Cb * N_ * 4);
    double* qpart  = (double*)alloc((size_t)Cb * 63 * 9 * 8);
    float*  ev     = (float*) alloc((size_t)Cb * E_ * AA_ * 4);

    int sc = (Cb < SC) ? Cb : SC;

    for (int b0 = 0; b0 < B_; b0 += Cb) {
        k_node<<<Cb * N_, 128, 0, stream>>>(obs, W1n, b1n, W2n, b2n, W1e, b1e,
                                            Hf, Ht, nv, q, a_hist, b0);
        k_edge<<<dim3((E_ + ET - 1) / ET, Cb), 192, 0, stream>>>(Hf, Ht, W2e, b2e, ev);
        // iteration loop over LLC-sized sub-chunks: identical arithmetic,
        // just smaller working set (ev 74MB + msgs) so re-reads hit L3
        for (int bo = 0; bo < Cb; bo += sc) {
            const float* evs = ev  + (size_t)bo * E_ * AA_;
            const float* nvs = nv  + (size_t)bo * N_ * A_;
            float* qs   = q   + (size_t)bo * N_ * A_;
            float* mfs  = mf  + (size_t)bo * E_ * A_;
            float* mfTs = mfT + (size_t)bo * N_ * 63 * A_;
            float* mbs  = mb  + (size_t)bo * E_ * A_;
            for (int it = 0; it < ITERS_; ++it) {
                k_msg<<<dim3(E_ / EB, sc), 128, 0, stream>>>(evs, qs, mfs, mfTs, mbs, it == 0);
                k_qupd<<<dim3(8, sc), 256, 0, stream>>>(nvs, mfTs, mbs, qs,
                        a_hist + (size_t)(1 + it) * Cb * N_ + (size_t)bo * N_);
            }
        }
        k_evalx<<<dim3(63, Cb), 576, 0, stream>>>(ev, a_hist, qpart, Cb);
        k_select<<<Cb, 64, 0, stream>>>(qpart, nv, a_hist, out, b0, Cb);
    }
}

// Round 10
// 964.858 us; speedup vs baseline: 1.1078x; 1.1078x over previous
//
#include <hip/hip_runtime.h>

#define B_    128
#define N_    64
#define D_    64
#define A_    12
#define H_    128
#define E_    4032   // N*(N-1)
#define AA_   144    // A*A
#define ITERS_ 8
#define ET    128    // edge tile (edge-vals kernel)
#define EB    32     // edges per block (msg kernel)
#define KC    32     // PINNED: KC=32 -> 140us. KC=16 -> 147 (R7); reg-prefetch -> 158 (R6).

// PINNED decisions (measured):
//  - k_msg dual-write (mf e-order + mfT to-order + mb): R7 loop=679us.
//    mfT-gather (drop mf): +27us (R8). DO NOT remove mf.
//  - full-Cb iteration loop: sub-chunking SC=32 cost +83us (R9). DO NOT sub-chunk.

typedef float f4_t __attribute__((ext_vector_type(4)));

// e -> (from,to): pairs are i-major, j skipping i
__device__ __forceinline__ void edge_nodes(int e, int& fr, int& to) {
    fr = e / 63;
    int rr = e - fr * 63;
    to = rr + (rr >= fr ? 1 : 0);
}

// ---------------------------------------------------------------------------
// Kernel 1: per-(b,n) node MLP + edge-GEMM1 decomposition. Writes a_hist[0].
// ---------------------------------------------------------------------------
__global__ __launch_bounds__(128) void k_node(
    const float* __restrict__ obs,
    const float* __restrict__ W1n, const float* __restrict__ b1n,
    const float* __restrict__ W2n, const float* __restrict__ b2n,
    const float* __restrict__ W1e, const float* __restrict__ b1e,
    float* __restrict__ Hf, float* __restrict__ Ht,
    float* __restrict__ nv, float* __restrict__ q, int* __restrict__ a0,
    int b0)
{
    int bn = blockIdx.x;      // local (b*64+n)
    int t  = threadIdx.x;     // 0..127
    __shared__ float s_obs[D_];
    __shared__ float s_hid[H_];
    __shared__ float s_nv[A_];
    if (t < D_) s_obs[t] = obs[(size_t)(b0 * N_ + bn) * D_ + t];
    __syncthreads();
    float an  = b1n[t];
    float af  = b1e[t];
    float at_ = 0.f;
    for (int k = 0; k < D_; ++k) {
        float o = s_obs[k];
        an  = fmaf(o, W1n[k * H_ + t], an);
        af  = fmaf(o, W1e[k * H_ + t], af);
        at_ = fmaf(o, W1e[(D_ + k) * H_ + t], at_);
    }
    s_hid[t] = fmaxf(an, 0.f);
    Hf[bn * H_ + t] = af;
    Ht[bn * H_ + t] = at_;
    __syncthreads();
    if (t < A_) {
        float acc = b2n[t];
        for (int k = 0; k < H_; ++k) acc = fmaf(s_hid[k], W2n[k * A_ + t], acc);
        s_nv[t] = acc;
        nv[bn * A_ + t] = acc;
        q[bn * A_ + t]  = acc * (1.0f / N_);
    }
    __syncthreads();
    if (t == 0) {
        float best = s_nv[0]; int bi = 0;
        for (int a = 1; a < A_; ++a) if (s_nv[a] > best) { best = s_nv[a]; bi = a; }
        a0[bn] = bi;
    }
}

// ---------------------------------------------------------------------------
// Kernel 2: edge_vals = relu(Hf[from]+Ht[to]) @ W2e + b2e.
// EXACT round-5 structure (KC=32, plain staged loop): measured 140us. PINNED.
// ---------------------------------------------------------------------------
__global__ __launch_bounds__(192) void k_edge(
    const float* __restrict__ Hf, const float* __restrict__ Ht,
    const float* __restrict__ W2e, const float* __restrict__ b2e,
    float* __restrict__ ev)
{
    __shared__ float s_w[KC * AA_];
    __shared__ float s_hT[KC * ET];
    __shared__ float s_b2[AA_];
    int t  = threadIdx.x;
    int b  = blockIdx.y;              // local batch
    int e0 = blockIdx.x * ET;
    int nE = min(ET, E_ - e0);

    if (t < AA_) s_b2[t] = b2e[t];

    int e_a = t & 127, kq_a = t >> 7;
    int fr_a = 0, to_a = 0;
    bool va = (e_a < nE);
    if (va) edge_nodes(e0 + e_a, fr_a, to_a);
    bool hb = (t < 64);
    int e_b = t + 64;
    int fr_b = 0, to_b = 0;
    bool vb = hb && (e_b < nE);
    if (vb) edge_nodes(e0 + e_b, fr_b, to_b);

    const float* HfB = Hf + (size_t)b * N_ * H_;
    const float* HtB = Ht + (size_t)b * N_ * H_;

    int cg = t % 12, rg = t / 12, rbase = rg * 8;
    float acc[8][12];
#pragma unroll
    for (int i = 0; i < 8; ++i)
#pragma unroll
        for (int j = 0; j < 12; ++j) acc[i][j] = 0.f;

    for (int kc = 0; kc < H_ / KC; ++kc) {
        __syncthreads();   // protect previous chunk's reads before overwrite
        const f4_t* wsrc = (const f4_t*)(W2e + kc * KC * AA_);
#pragma unroll
        for (int i = 0; i < 6; ++i)
            *(f4_t*)&s_w[(t + i * 192) * 4] = wsrc[t + i * 192];
        {
            int kk = kc * KC + kq_a * 16;
            if (va) {
                const f4_t* pf = (const f4_t*)(HfB + fr_a * H_ + kk);
                const f4_t* pt = (const f4_t*)(HtB + to_a * H_ + kk);
#pragma unroll
                for (int m = 0; m < 4; ++m) {
                    f4_t x = pf[m], y = pt[m];
                    s_hT[(kq_a * 16 + 4 * m + 0) * ET + e_a] = fmaxf(x.x + y.x, 0.f);
                    s_hT[(kq_a * 16 + 4 * m + 1) * ET + e_a] = fmaxf(x.y + y.y, 0.f);
                    s_hT[(kq_a * 16 + 4 * m + 2) * ET + e_a] = fmaxf(x.z + y.z, 0.f);
                    s_hT[(kq_a * 16 + 4 * m + 3) * ET + e_a] = fmaxf(x.w + y.w, 0.f);
                }
            } else {
#pragma unroll
                for (int m = 0; m < 16; ++m) s_hT[(kq_a * 16 + m) * ET + e_a] = 0.f;
            }
            if (hb) {
                int kk2 = kc * KC + 16;
                if (vb) {
                    const f4_t* pf = (const f4_t*)(HfB + fr_b * H_ + kk2);
                    const f4_t* pt = (const f4_t*)(HtB + to_b * H_ + kk2);
#pragma unroll
                    for (int m = 0; m < 4; ++m) {
                        f4_t x = pf[m], y = pt[m];
                        s_hT[(16 + 4 * m + 0) * ET + e_b] = fmaxf(x.x + y.x, 0.f);
                        s_hT[(16 + 4 * m + 1) * ET + e_b] = fmaxf(x.y + y.y, 0.f);
                        s_hT[(16 + 4 * m + 2) * ET + e_b] = fmaxf(x.z + y.z, 0.f);
                        s_hT[(16 + 4 * m + 3) * ET + e_b] = fmaxf(x.w + y.w, 0.f);
                    }
                } else {
#pragma unroll
                    for (int m = 0; m < 16; ++m) s_hT[(16 + m) * ET + e_b] = 0.f;
                }
            }
        }
        __syncthreads();

#pragma unroll 2
        for (int k = 0; k < KC; ++k) {
            const float* hp = &s_hT[k * ET + rbase];
            f4_t h0 = *(const f4_t*)hp;
            f4_t h1 = *(const f4_t*)(hp + 4);
            const float* wp = &s_w[k * AA_ + cg * 12];
            f4_t w0 = *(const f4_t*)wp;
            f4_t w1 = *(const f4_t*)(wp + 4);
            f4_t w2 = *(const f4_t*)(wp + 8);
            float hv[8]  = {h0.x,h0.y,h0.z,h0.w,h1.x,h1.y,h1.z,h1.w};
            float wv[12] = {w0.x,w0.y,w0.z,w0.w,w1.x,w1.y,w1.z,w1.w,w2.x,w2.y,w2.z,w2.w};
#pragma unroll
            for (int i = 0; i < 8; ++i)
#pragma unroll
                for (int j = 0; j < 12; ++j)
                    acc[i][j] = fmaf(hv[i], wv[j], acc[i][j]);
        }
    }

    size_t obase = (size_t)(b * E_ + e0) * AA_;
#pragma unroll
    for (int i = 0; i < 8; ++i) {
        int e = rbase + i;
        if (e < nE) {
            float* op = &ev[obase + (size_t)e * AA_ + cg * 12];
#pragma unroll
            for (int j = 0; j < 12; j += 4) {
                f4_t o;
                o.x = acc[i][j + 0] + s_b2[cg * 12 + j + 0];
                o.y = acc[i][j + 1] + s_b2[cg * 12 + j + 1];
                o.z = acc[i][j + 2] + s_b2[cg * 12 + j + 2];
                o.w = acc[i][j + 3] + s_b2[cg * 12 + j + 3];
                *(f4_t*)(op + j) = o;
            }
        }
    }
}

// ---------------------------------------------------------------------------
// Kernel 3: fused fwd+bwd message update (R7 dual-write form, PINNED).
// ---------------------------------------------------------------------------
__global__ __launch_bounds__(128) void k_msg(
    const float* __restrict__ ev, const float* __restrict__ q,
    float* __restrict__ mf, float* __restrict__ mfT,
    float* __restrict__ mb, int first)
{
    __shared__ float s_c1[EB * A_], s_c2[EB * A_];
    __shared__ float s_mf[EB * A_], s_mb[EB * A_];
    int t  = threadIdx.x;
    int b  = blockIdx.y;
    int e0 = blockIdx.x * EB;

    // staging: 96 f4 per array (32 edges x 12 floats)
    if (t < 96) {
        int e = t / 3, m = t - (t / 3) * 3;
        int eg = e0 + e, fr, to; edge_nodes(eg, fr, to);
        f4_t qf = ((const f4_t*)(q + ((size_t)b * N_ + fr) * A_))[m];
        f4_t qt = ((const f4_t*)(q + ((size_t)b * N_ + to) * A_))[m];
        if (!first) {
            f4_t mbo = ((const f4_t*)(mb + ((size_t)b * E_ + e0) * A_))[t];
            f4_t mfo = ((const f4_t*)(mf + ((size_t)b * E_ + e0) * A_))[t];
            qf.x -= mbo.x; qf.y -= mbo.y; qf.z -= mbo.z; qf.w -= mbo.w;
            qt.x -= mfo.x; qt.y -= mfo.y; qt.z -= mfo.z; qt.w -= mfo.w;
        }
        ((f4_t*)s_c1)[t] = qf;
        ((f4_t*)s_c2)[t] = qt;
    }

    int e = t >> 2, s = t & 3;
    int eg = e0 + e, fr_o, to_o; edge_nodes(eg, fr_o, to_o);
    const float* wp = ev + ((size_t)(b * E_ + eg)) * AA_ + s * 36;
    f4_t wv[9];
#pragma unroll
    for (int i = 0; i < 9; ++i) wv[i] = ((const f4_t*)wp)[i];
    __syncthreads();

    const float invE = 1.0f / (float)E_;
    float fo[12];
#pragma unroll
    for (int j = 0; j < 12; ++j) fo[j] = -1e30f;
#pragma unroll
    for (int r = 0; r < 3; ++r) {
        float c1v = s_c1[e * A_ + s * 3 + r];
#pragma unroll
        for (int j = 0; j < 12; ++j) {
            int li = r * 12 + j;
            float w = wv[li >> 2][li & 3];
            fo[j] = fmaxf(fo[j], c1v + w * invE);
        }
    }
#pragma unroll
    for (int j = 0; j < 12; ++j) {
        float v = fo[j];
        v = fmaxf(v, __shfl_xor(v, 1));
        v = fmaxf(v, __shfl_xor(v, 2));
        fo[j] = v;
    }
    float fsum = 0.f;
#pragma unroll
    for (int i = 0; i < 3; ++i) fsum += fo[s * 3 + i];
    fsum += __shfl_xor(fsum, 1); fsum += __shfl_xor(fsum, 2);
    float fmean = fsum / 12.0f;

    float c2r[12];
#pragma unroll
    for (int j = 0; j < 12; ++j) c2r[j] = s_c2[e * A_ + j];
    float ba[3];
    float bsum = 0.f;
#pragma unroll
    for (int r = 0; r < 3; ++r) {
        float m = -1e30f;
#pragma unroll
        for (int j = 0; j < 12; ++j) {
            int li = r * 12 + j;
            float w = wv[li >> 2][li & 3];
            m = fmaxf(m, c2r[j] + w * invE);
        }
        ba[r] = m; bsum += m;
    }
    bsum += __shfl_xor(bsum, 1); bsum += __shfl_xor(bsum, 2);
    float bmean = bsum / 12.0f;

#pragma unroll
    for (int i = 0; i < 3; ++i) {
        s_mf[e * A_ + s * 3 + i] = fo[s * 3 + i] - fmean;
        s_mb[e * A_ + s * 3 + i] = ba[i] - bmean;
    }
    // mfT: to-major layout, rank = fr - (fr>to); 4 threads write 48B/edge
    {
        int rr2 = fr_o - (fr_o > to_o ? 1 : 0);
        float* mtp = mfT + (((size_t)b * N_ + to_o) * 63 + rr2) * A_ + s * 3;
        mtp[0] = fo[s * 3 + 0] - fmean;
        mtp[1] = fo[s * 3 + 1] - fmean;
        mtp[2] = fo[s * 3 + 2] - fmean;
    }
    __syncthreads();
    if (t < 96) {
        size_t gbase = (size_t)(b * E_ + e0) * A_;
        ((f4_t*)(mf + gbase))[t] = ((f4_t*)s_mf)[t];
        ((f4_t*)(mb + gbase))[t] = ((f4_t*)s_mb)[t];
    }
}

// ---------------------------------------------------------------------------
// Kernel 4: q = nv/N + seq-sum(mfT row) + seq-sum(mb row); argmax -> a_out.
// ---------------------------------------------------------------------------
__global__ __launch_bounds__(256) void k_qupd(
    const float* __restrict__ nv, const float* __restrict__ mfT,
    const float* __restrict__ mb,
    float* __restrict__ q, int* __restrict__ a_out)
{
    __shared__ float s_f[8 * 756];
    __shared__ float s_b[8 * 756];
    __shared__ float s_q[8][A_];
    int t  = threadIdx.x;
    int b  = blockIdx.y;
    int n0 = blockIdx.x * 8;
    const f4_t* src_f = (const f4_t*)(mfT + ((size_t)b * N_ + n0) * 63 * A_);
    const f4_t* src_b = (const f4_t*)(mb + ((size_t)b * E_ + n0 * 63) * A_);
#pragma unroll
    for (int i = 0; i < 6; ++i) {
        int gi = t + i * 256;                  // 1512 f4 total
        if (gi < 1512) {
            ((f4_t*)s_f)[gi] = src_f[gi];
            ((f4_t*)s_b)[gi] = src_b[gi];
        }
    }
    __syncthreads();
    int nl = t / 12, a = t - nl * 12;
    if (t < 96) {
        int n = n0 + nl;
        float acc = nv[(b * N_ + n) * A_ + a] * (1.0f / N_);
        const float* pf = s_f + nl * 756 + a;
        for (int i = 0; i < 63; ++i) acc += pf[i * 12];
        const float* pb = s_b + nl * 756 + a;
        for (int i = 0; i < 63; ++i) acc += pb[i * 12];
        q[(b * N_ + n) * A_ + a] = acc;
        s_q[nl][a] = acc;
    }
    __syncthreads();
    if (t < 8) {
        float best = s_q[t][0]; int bi = 0;
        for (int aa = 1; aa < A_; ++aa) if (s_q[t][aa] > best) { best = s_q[t][aa]; bi = aa; }
        a_out[b * N_ + n0 + t] = bi;
    }
}

// ---------------------------------------------------------------------------
// Kernel 5: stream ev rows once; 9 waves = 9 candidates; fp64 tile partials.
// ---------------------------------------------------------------------------
__global__ __launch_bounds__(576) void k_evalx(
    const float* __restrict__ ev, const int* __restrict__ a_hist,
    double* __restrict__ qpart, int Cb)
{
    __shared__ float s_ev[64 * 148];
    __shared__ int   s_aa[9][N_];
    int t = threadIdx.x, tile = blockIdx.x, b = blockIdx.y;
    const f4_t* src = (const f4_t*)(ev + ((size_t)b * E_ + tile * 64) * AA_);
#pragma unroll
    for (int i = 0; i < 4; ++i) {
        int gi = t + i * 576;                  // 2304 f4 exactly
        int e = gi / 36, k = gi - e * 36;
        *(f4_t*)&s_ev[e * 148 + k * 4] = src[gi];
    }
    s_aa[t / 64][t % 64] = a_hist[((size_t)(t / 64) * Cb + b) * N_ + (t % 64)];
    __syncthreads();
    int c = t / 64, el = t % 64;
    int eg = tile * 64 + el;
    int fr, to; edge_nodes(eg, fr, to);
    double v = (double)s_ev[el * 148 + s_aa[c][fr] * A_ + s_aa[c][to]];
#pragma unroll
    for (int off = 1; off < 64; off <<= 1) v += __shfl_xor(v, off);
    if (el == 0) qpart[((size_t)b * 63 + tile) * 9 + c] = v;
}

// ---------------------------------------------------------------------------
// Kernel 6: per-b: fp64 candidate totals (tiles asc + nv part), strict-> scan.
// ---------------------------------------------------------------------------
__global__ __launch_bounds__(64) void k_select(
    const double* __restrict__ qpart, const float* __restrict__ nv,
    const int* __restrict__ a_hist, float* __restrict__ out, int b0, int Cb)
{
    int b = blockIdx.x, t = threadIdx.x;
    __shared__ double s_qv[9];
    __shared__ int s_best;
    if (t < 9) {
        double s = 0.0;
        const double* qp = qpart + (size_t)b * 63 * 9 + t;
        for (int i = 0; i < 63; ++i) s += qp[i * 9];
        const int* ah = a_hist + ((size_t)t * Cb + b) * N_;
        const float* nb = nv + (size_t)b * N_ * A_;
        double ns = 0.0;
        for (int n = 0; n < N_; ++n) ns += (double)nb[n * A_ + ah[n]];
        s_qv[t] = ns / 64.0 + s / 4032.0;
    }
    __syncthreads();
    if (t == 0) {
        double best = s_qv[0]; int bi = 0;
        for (int c = 1; c <= ITERS_; ++c) if (s_qv[c] > best) { best = s_qv[c]; bi = c; }
        out[b0 + b] = (float)best;
        s_best = bi;
    }
    __syncthreads();
    out[B_ + (size_t)(b0 + b) * N_ + t] = (float)a_hist[((size_t)s_best * Cb + b) * N_ + t];
}

// Diagnostic: encode ws_size (MB) into out[0] so a failed absmax reveals it.
__global__ void k_diag(float* out, float v, int n) {
    int i = blockIdx.x * 256 + threadIdx.x;
    if (i < n) out[i] = (i == 0) ? v : -10000.0f;
}

extern "C" void kernel_launch(void* const* d_in, const int* in_sizes, int n_in,
                              void* d_out, int out_size, void* d_ws, size_t ws_size,
                              hipStream_t stream) {
    const float* obs = (const float*)d_in[0];
    const float* W1n = (const float*)d_in[1];
    const float* b1n = (const float*)d_in[2];
    const float* W2n = (const float*)d_in[3];
    const float* b2n = (const float*)d_in[4];
    const float* W1e = (const float*)d_in[5];
    const float* b1e = (const float*)d_in[6];
    const float* W2e = (const float*)d_in[7];
    const float* b2e = (const float*)d_in[8];
    float* out = (float*)d_out;
    (void)in_sizes; (void)n_in; (void)out_size;

    // per-batch bytes: Hf+Ht 65536, nv+q 6144, mf+mfT+mb 580608, a_hist 2304,
    // qpart 4536, ev 2322432 => 2981560; plus per-buffer align slack
    auto need = [](int Cb) -> size_t { return (size_t)Cb * 2981560u + 16384u; };

    int Cb = 0;
    for (int c = B_; c >= 8; c >>= 1) {
        if (ws_size >= need(c)) { Cb = c; break; }
    }
    if (Cb == 0) {
        k_diag<<<(B_ + B_ * N_ + 255) / 256, 256, 0, stream>>>(
            out, (float)(ws_size >> 20), B_ + B_ * N_);
        return;
    }

    char* ws = (char*)d_ws;
    size_t off = 0;
    auto alloc = [&](size_t bytes) { void* p = ws + off; off += (bytes + 255) & ~(size_t)255; return p; };
    float*  Hf     = (float*) alloc((size_t)Cb * N_ * H_ * 4);
    float*  Ht     = (float*) alloc((size_t)Cb * N_ * H_ * 4);
    float*  nv     = (float*) alloc((size_t)Cb * N_ * A_ * 4);
    float*  q      = (float*) alloc((size_t)Cb * N_ * A_ * 4);
    float*  mf     = (float*) alloc((size_t)Cb * E_ * A_ * 4);
    float*  mfT    = (float*) alloc((size_t)Cb * N_ * 63 * A_ * 4);
    float*  mb     = (float*) alloc((size_t)Cb * E_ * A_ * 4);
    int*    a_hist = (int*)   alloc((size_t)(1 + ITERS_) * Cb * N_ * 4);
    double* qpart  = (double*)alloc((size_t)Cb * 63 * 9 * 8);
    float*  ev     = (float*) alloc((size_t)Cb * E_ * AA_ * 4);

    for (int b0 = 0; b0 < B_; b0 += Cb) {
        k_node<<<Cb * N_, 128, 0, stream>>>(obs, W1n, b1n, W2n, b2n, W1e, b1e,
                                            Hf, Ht, nv, q, a_hist, b0);
        k_edge<<<dim3((E_ + ET - 1) / ET, Cb), 192, 0, stream>>>(Hf, Ht, W2e, b2e, ev);
        for (int it = 0; it < ITERS_; ++it) {
            k_msg<<<dim3(E_ / EB, Cb), 128, 0, stream>>>(ev, q, mf, mfT, mb, it == 0);
            k_qupd<<<dim3(8, Cb), 256, 0, stream>>>(nv, mfT, mb, q,
                                                    a_hist + (size_t)(1 + it) * Cb * N_);
        }
        k_evalx<<<dim3(63, Cb), 576, 0, stream>>>(ev, a_hist, qpart, Cb);
        k_select<<<Cb, 64, 0, stream>>>(qpart, nv, a_hist, out, b0, Cb);
    }
}